// Round 1
// baseline (1695.473 us; speedup 1.0000x reference)
//
#include <hip/hip_runtime.h>
#include <math.h>

#define N_NODES 10000
#define N_EDGES 160000
#define F 128
#define TE 16   // edges per block in the fused edge kernel

__device__ __forceinline__ float nsilu(float x) {
    // silu(x) * 1.679177
    return 1.679177f * (x / (1.0f + expf(-x)));
}

__device__ __forceinline__ int species_of(int n, const int* __restrict__ counts) {
    int c0 = counts[0];
    int c01 = c0 + counts[1];
    int c012 = c01 + counts[2];
    return (n >= c0) + (n >= c01) + (n >= c012);
}

// ---------------------------------------------------------------------------
// Kernel 1: per-node linear_up (s, v) + species-indexed self connection.
// grid = N_NODES blocks, 128 threads (one per output feature g).
// ---------------------------------------------------------------------------
__global__ __launch_bounds__(128) void k_node_up(
    const float* __restrict__ ns,     // [N,F]
    const float* __restrict__ nv,     // [N,F,3]
    const float* __restrict__ Wup_s,  // [F,F]
    const float* __restrict__ Wup_v,  // [F,F]
    const float* __restrict__ Wz,     // [S,F,F]
    const int* __restrict__ counts,   // [S]
    float* __restrict__ s_buf,        // [N,F]
    float* __restrict__ v_buf,        // [N,F,3]
    float* __restrict__ selfc)        // [N,F]
{
    int n = blockIdx.x;
    int g = threadIdx.x;
    __shared__ float sh_s[F];
    __shared__ float sh_v[F * 3];

    sh_s[g] = ns[n * F + g];
    for (int j = g; j < F * 3; j += F) sh_v[j] = nv[n * F * 3 + j];
    __syncthreads();

    int spec = species_of(n, counts);
    const float* wz = Wz + spec * F * F;

    float acc_self = 0.f, acc_s = 0.f, a0 = 0.f, a1 = 0.f, a2 = 0.f;
    for (int f = 0; f < F; ++f) {
        float xs = sh_s[f];
        acc_self += xs * wz[f * F + g];
        acc_s    += xs * Wup_s[f * F + g];
        float w = Wup_v[f * F + g];
        a0 += sh_v[f * 3 + 0] * w;
        a1 += sh_v[f * 3 + 1] * w;
        a2 += sh_v[f * 3 + 2] * w;
    }
    const float inv_sqrtF = 0.08838834764831845f;  // 1/sqrt(128)
    selfc[n * F + g] = acc_self * inv_sqrtF;
    s_buf[n * F + g] = acc_s * inv_sqrtF;
    v_buf[(n * F + g) * 3 + 0] = a0 * inv_sqrtF;
    v_buf[(n * F + g) * 3 + 1] = a1 * inv_sqrtF;
    v_buf[(n * F + g) * 3 + 2] = a2 * inv_sqrtF;
}

// ---------------------------------------------------------------------------
// Kernel 2 (fused): radial MLP -> TP weights -> channelwise TP -> atomic scatter.
// grid = N_EDGES/TE blocks, 256 threads. mix tile lives in LDS (never hits HBM).
// ---------------------------------------------------------------------------
__global__ __launch_bounds__(256) void k_edge(
    const float* __restrict__ vectors,   // [E,3]
    const float* __restrict__ re,        // [E,8]
    const float* __restrict__ W1, const float* __restrict__ b1,   // [8,64],[64]
    const float* __restrict__ W2, const float* __restrict__ b2,   // [64,64],[64]
    const float* __restrict__ W3, const float* __restrict__ b3,   // [64,64],[64]
    const float* __restrict__ W4, const float* __restrict__ b4,   // [64,512],[512]
    const int* __restrict__ senders,
    const int* __restrict__ receivers,
    const float* __restrict__ s_buf,     // [N,F]
    const float* __restrict__ v_buf,     // [N,F,3]
    float* __restrict__ agg_s,           // [N,2F]
    float* __restrict__ agg_v)           // [N,2F,3]
{
    __shared__ float sh_re[TE][8];
    __shared__ float sh_ha[TE][64];
    __shared__ float sh_hb[TE][64];
    __shared__ float sh_mix[TE][512];

    int t = threadIdx.x;
    int e0 = blockIdx.x * TE;

    for (int j = t; j < TE * 8; j += 256) sh_re[j >> 3][j & 7] = re[e0 * 8 + j];
    __syncthreads();

    // h1 = nsilu(re @ W1 + b1)
    for (int idx = t; idx < TE * 64; idx += 256) {
        int e = idx >> 6, u = idx & 63;
        float a = b1[u];
        #pragma unroll
        for (int k = 0; k < 8; ++k) a += sh_re[e][k] * W1[k * 64 + u];
        sh_ha[e][u] = nsilu(a);
    }
    __syncthreads();

    // h2 = nsilu(h1 @ W2 + b2)
    for (int idx = t; idx < TE * 64; idx += 256) {
        int e = idx >> 6, u = idx & 63;
        float a = b2[u];
        for (int k = 0; k < 64; ++k) a += sh_ha[e][k] * W2[k * 64 + u];
        sh_hb[e][u] = nsilu(a);
    }
    __syncthreads();

    // h3 = nsilu(h2 @ W3 + b3)  (into sh_ha)
    for (int idx = t; idx < TE * 64; idx += 256) {
        int e = idx >> 6, u = idx & 63;
        float a = b3[u];
        for (int k = 0; k < 64; ++k) a += sh_hb[e][k] * W3[k * 64 + u];
        sh_ha[e][u] = nsilu(a);
    }
    __syncthreads();

    // mix = h3 @ W4 + b4   [TE,512] in LDS
    for (int idx = t; idx < TE * 512; idx += 256) {
        int e = idx >> 9, g = idx & 511;
        float a = b4[g];
        for (int k = 0; k < 64; ++k) a += sh_ha[e][k] * W4[k * 512 + g];
        sh_mix[e][g] = a;
    }
    __syncthreads();

    // channelwise TP + atomic scatter
    const float inv_sqrt3 = 0.5773502691896258f;
    for (int idx = t; idx < TE * F; idx += 256) {
        int e = idx >> 7, f = idx & (F - 1);
        int ge = e0 + e;
        int snd = senders[ge];
        int rcv = receivers[ge];
        float vx = vectors[ge * 3 + 0];
        float vy = vectors[ge * 3 + 1];
        float vz = vectors[ge * 3 + 2];
        float rn = sqrtf(vx * vx + vy * vy + vz * vz) + 1e-12f;
        float y0 = vx / rn, y1 = vy / rn, y2 = vz / rn;

        float sg  = s_buf[snd * F + f];
        float vg0 = v_buf[(snd * F + f) * 3 + 0];
        float vg1 = v_buf[(snd * F + f) * 3 + 1];
        float vg2 = v_buf[(snd * F + f) * 3 + 2];

        float m0 = sh_mix[e][0 * F + f];
        float m1 = sh_mix[e][1 * F + f];
        float m2 = sh_mix[e][2 * F + f];
        float m3 = sh_mix[e][3 * F + f];

        float ms0 = m0 * sg;
        float dot = vg0 * y0 + vg1 * y1 + vg2 * y2;
        float ms3 = m3 * dot * inv_sqrt3;
        float w1s = m1 * sg;

        atomicAdd(&agg_s[rcv * 2 * F + f], ms0);
        atomicAdd(&agg_s[rcv * 2 * F + F + f], ms3);
        atomicAdd(&agg_v[(rcv * 2 * F + f) * 3 + 0], w1s * y0);
        atomicAdd(&agg_v[(rcv * 2 * F + f) * 3 + 1], w1s * y1);
        atomicAdd(&agg_v[(rcv * 2 * F + f) * 3 + 2], w1s * y2);
        atomicAdd(&agg_v[(rcv * 2 * F + F + f) * 3 + 0], m2 * vg0);
        atomicAdd(&agg_v[(rcv * 2 * F + F + f) * 3 + 1], m2 * vg1);
        atomicAdd(&agg_v[(rcv * 2 * F + F + f) * 3 + 2], m2 * vg2);
    }
}

// ---------------------------------------------------------------------------
// Kernel 3: linear_down + symmetric contraction + post linear + readout.
// grid = N_NODES blocks, 128 threads.
// ---------------------------------------------------------------------------
__global__ __launch_bounds__(128) void k_node_post(
    const float* __restrict__ agg_s,   // [N,2F]
    const float* __restrict__ agg_v,   // [N,2F,3]
    const float* __restrict__ Wds,     // [2F,F]
    const float* __restrict__ Wdv,     // [2F,F]
    const float* __restrict__ Wsc,     // [S,5,F]
    const float* __restrict__ Wpost,   // [F,F]
    const float* __restrict__ Wro1,    // [F,16]
    const float* __restrict__ Wro2,    // [16,1]
    const float* __restrict__ selfc,   // [N,F]
    const int* __restrict__ counts,
    float* __restrict__ out)           // [N] outputs then [N,F] feats
{
    int n = blockIdx.x;
    int g = threadIdx.x;
    __shared__ float sh_as[2 * F];
    __shared__ float sh_av[2 * F * 3];
    __shared__ float sh_sc[F];
    __shared__ float sh_feat[F];
    __shared__ float sh_hr[16];

    sh_as[g]     = agg_s[n * 2 * F + g];
    sh_as[F + g] = agg_s[n * 2 * F + F + g];
    for (int j = g; j < 2 * F * 3; j += F) sh_av[j] = agg_v[n * 2 * F * 3 + j];
    __syncthreads();

    float s2 = 0.f, v0 = 0.f, v1 = 0.f, v2 = 0.f;
    for (int k = 0; k < 2 * F; ++k) {
        float w = Wds[k * F + g];
        s2 += sh_as[k] * w;
        float wv = Wdv[k * F + g];
        v0 += sh_av[k * 3 + 0] * wv;
        v1 += sh_av[k * 3 + 1] * wv;
        v2 += sh_av[k * 3 + 2] * wv;
    }
    // EPS * 1/sqrt(2F) = 0.17677669529663687 / 16
    const float scale = 0.17677669529663687f * 0.0625f;
    s2 *= scale; v0 *= scale; v1 *= scale; v2 *= scale;
    float vv = v0 * v0 + v1 * v1 + v2 * v2;

    int spec = species_of(n, counts);
    const float* wsc = Wsc + spec * 5 * F;
    float sc = wsc[0 * F + g] * s2
             + wsc[1 * F + g] * (s2 * s2)
             + wsc[2 * F + g] * vv
             + wsc[3 * F + g] * (s2 * s2 * s2)
             + wsc[4 * F + g] * (s2 * vv);
    sh_sc[g] = sc;
    __syncthreads();

    const float inv_sqrtF = 0.08838834764831845f;
    float acc = 0.f;
    for (int f = 0; f < F; ++f) acc += sh_sc[f] * Wpost[f * F + g];
    float feat = acc * inv_sqrtF + selfc[n * F + g];
    out[N_NODES + n * F + g] = feat;
    sh_feat[g] = feat;
    __syncthreads();

    if (g < 16) {
        float a = 0.f;
        for (int f = 0; f < F; ++f) a += sh_feat[f] * Wro1[f * 16 + g];
        sh_hr[g] = nsilu(a * inv_sqrtF);
    }
    __syncthreads();

    if (g == 0) {
        float a = 0.f;
        #pragma unroll
        for (int j = 0; j < 16; ++j) a += sh_hr[j] * Wro2[j];
        out[n] = a * 0.25f;   // 1/sqrt(16)
    }
}

// ---------------------------------------------------------------------------

extern "C" void kernel_launch(void* const* d_in, const int* in_sizes, int n_in,
                              void* d_out, int out_size, void* d_ws, size_t ws_size,
                              hipStream_t stream) {
    const float* vectors      = (const float*)d_in[0];
    const float* node_scalars = (const float*)d_in[1];
    const float* node_vectors = (const float*)d_in[2];
    const float* radial       = (const float*)d_in[3];
    const float* W_up_s       = (const float*)d_in[4];
    const float* W_up_v       = (const float*)d_in[5];
    const float* W1 = (const float*)d_in[6];
    const float* b1 = (const float*)d_in[7];
    const float* W2 = (const float*)d_in[8];
    const float* b2 = (const float*)d_in[9];
    const float* W3 = (const float*)d_in[10];
    const float* b3 = (const float*)d_in[11];
    const float* W4 = (const float*)d_in[12];
    const float* b4 = (const float*)d_in[13];
    const float* Wds  = (const float*)d_in[14];
    const float* Wdv  = (const float*)d_in[15];
    const float* Wz   = (const float*)d_in[16];
    const float* Wsc  = (const float*)d_in[17];
    const float* Wpost= (const float*)d_in[18];
    const float* Wro1 = (const float*)d_in[19];
    const float* Wro2 = (const float*)d_in[20];
    const int* senders   = (const int*)d_in[21];
    const int* receivers = (const int*)d_in[22];
    const int* counts    = (const int*)d_in[23];
    float* out = (float*)d_out;

    // workspace layout (floats)
    float* ws     = (float*)d_ws;
    float* s_buf  = ws;                        // N*F
    float* v_buf  = s_buf + N_NODES * F;       // N*F*3
    float* selfc  = v_buf + N_NODES * F * 3;   // N*F
    float* agg_s  = selfc + N_NODES * F;       // N*2F
    float* agg_v  = agg_s + N_NODES * 2 * F;   // N*2F*3
    // total: N*F*(1+3+1+2+6) = 13*N*F floats = 66.56 MB

    // zero the aggregation buffers (they're poisoned before every launch)
    hipMemsetAsync(agg_s, 0, (size_t)N_NODES * 8 * F * sizeof(float), stream);

    k_node_up<<<N_NODES, 128, 0, stream>>>(
        node_scalars, node_vectors, W_up_s, W_up_v, Wz, counts,
        s_buf, v_buf, selfc);

    k_edge<<<N_EDGES / TE, 256, 0, stream>>>(
        vectors, radial, W1, b1, W2, b2, W3, b3, W4, b4,
        senders, receivers, s_buf, v_buf, agg_s, agg_v);

    k_node_post<<<N_NODES, 128, 0, stream>>>(
        agg_s, agg_v, Wds, Wdv, Wsc, Wpost, Wro1, Wro2, selfc, counts, out);
}

// Round 2
// 650.804 us; speedup vs baseline: 2.6052x; 2.6052x over previous
//
#include <hip/hip_runtime.h>
#include <hip/hip_bf16.h>
#include <math.h>

#define N_NODES 10000
#define N_EDGES 160000
#define F 128
#define NB 8          // nodes per block in node kernels
#define TE 256        // edges per block in k_mlp
#define HPAD 68       // padded row stride for h buffers (16B-aligned, bank-spread)

__device__ __forceinline__ float nsilu(float x) {
    return 1.679177f * (x / (1.0f + expf(-x)));
}

__device__ __forceinline__ void fma4(float4& a, float s, const float4& b) {
    a.x = fmaf(s, b.x, a.x); a.y = fmaf(s, b.y, a.y);
    a.z = fmaf(s, b.z, a.z); a.w = fmaf(s, b.w, a.w);
}

__device__ __forceinline__ int species_of(int n, const int* __restrict__ counts) {
    int c0 = counts[0];
    int c01 = c0 + counts[1];
    int c012 = c01 + counts[2];
    return (n >= c0) + (n >= c01) + (n >= c012);
}

// mix element store/load (fp32 or bf16 workspace)
__device__ __forceinline__ void store4m(float* p, const float4& v) { *(float4*)p = v; }
__device__ __forceinline__ void store4m(__hip_bfloat16* p, const float4& v) {
    __hip_bfloat16 tmp[4];
    tmp[0] = __float2bfloat16(v.x); tmp[1] = __float2bfloat16(v.y);
    tmp[2] = __float2bfloat16(v.z); tmp[3] = __float2bfloat16(v.w);
    *reinterpret_cast<uint2*>(p) = *reinterpret_cast<uint2*>(tmp);
}
__device__ __forceinline__ float loadm(const float* p) { return *p; }
__device__ __forceinline__ float loadm(const __hip_bfloat16* p) { return __bfloat162float(*p); }

// ---------------------------------------------------------------------------
// Kernel 1: per-node linear_up + species skip. NB nodes per block, 128 thr.
// ---------------------------------------------------------------------------
__global__ __launch_bounds__(128) void k_node_up(
    const float* __restrict__ ns, const float* __restrict__ nv,
    const float* __restrict__ Wup_s, const float* __restrict__ Wup_v,
    const float* __restrict__ Wz, const int* __restrict__ counts,
    float* __restrict__ s_buf, float* __restrict__ v_buf, float* __restrict__ selfc)
{
    const int n0 = blockIdx.x * NB;
    const int g = threadIdx.x;
    __shared__ float ss[NB][F];
    __shared__ float sv0[NB][F], sv1[NB][F], sv2[NB][F];

    #pragma unroll
    for (int i = 0; i < NB; ++i) {
        ss[i][g] = ns[(size_t)(n0 + i) * F + g];
        const float* vp = nv + (size_t)(n0 + i) * F * 3;
        sv0[i][g] = vp[g * 3 + 0];
        sv1[i][g] = vp[g * 3 + 1];
        sv2[i][g] = vp[g * 3 + 2];
    }
    __syncthreads();

    int spec0 = species_of(n0, counts);
    int specL = species_of(n0 + NB - 1, counts);
    bool uni = (spec0 == specL);
    const float* wzb = Wz + (size_t)spec0 * F * F;

    float accS[NB], accZ[NB], a0[NB], a1[NB], a2[NB];
    #pragma unroll
    for (int i = 0; i < NB; ++i) { accS[i]=0; accZ[i]=0; a0[i]=0; a1[i]=0; a2[i]=0; }

    for (int f4 = 0; f4 < F / 4; ++f4) {
        int f = f4 * 4;
        float ws0 = Wup_s[(f+0)*F+g], ws1 = Wup_s[(f+1)*F+g];
        float ws2 = Wup_s[(f+2)*F+g], ws3 = Wup_s[(f+3)*F+g];
        float wv0 = Wup_v[(f+0)*F+g], wv1 = Wup_v[(f+1)*F+g];
        float wv2 = Wup_v[(f+2)*F+g], wv3 = Wup_v[(f+3)*F+g];
        float wz0 = 0, wz1 = 0, wz2 = 0, wz3 = 0;
        if (uni) {
            wz0 = wzb[(f+0)*F+g]; wz1 = wzb[(f+1)*F+g];
            wz2 = wzb[(f+2)*F+g]; wz3 = wzb[(f+3)*F+g];
        }
        #pragma unroll
        for (int i = 0; i < NB; ++i) {
            float4 xs = *(const float4*)&ss[i][f];
            float4 x0 = *(const float4*)&sv0[i][f];
            float4 x1 = *(const float4*)&sv1[i][f];
            float4 x2 = *(const float4*)&sv2[i][f];
            accS[i] += xs.x*ws0 + xs.y*ws1 + xs.z*ws2 + xs.w*ws3;
            a0[i]   += x0.x*wv0 + x0.y*wv1 + x0.z*wv2 + x0.w*wv3;
            a1[i]   += x1.x*wv0 + x1.y*wv1 + x1.z*wv2 + x1.w*wv3;
            a2[i]   += x2.x*wv0 + x2.y*wv1 + x2.z*wv2 + x2.w*wv3;
            if (uni) accZ[i] += xs.x*wz0 + xs.y*wz1 + xs.z*wz2 + xs.w*wz3;
        }
    }
    if (!uni) {
        #pragma unroll
        for (int i = 0; i < NB; ++i) {
            const float* wz = Wz + (size_t)species_of(n0 + i, counts) * F * F;
            float a = 0;
            for (int f = 0; f < F; ++f) a += ss[i][f] * wz[f * F + g];
            accZ[i] = a;
        }
    }
    const float isf = 0.08838834764831845f;  // 1/sqrt(128)
    #pragma unroll
    for (int i = 0; i < NB; ++i) {
        size_t n = n0 + i;
        selfc[n * F + g] = accZ[i] * isf;
        s_buf[n * F + g] = accS[i] * isf;
        float* vp = v_buf + (n * F + g) * 3;
        vp[0] = a0[i] * isf; vp[1] = a1[i] * isf; vp[2] = a2[i] * isf;
    }
}

// ---------------------------------------------------------------------------
// CSR build
// ---------------------------------------------------------------------------
__global__ __launch_bounds__(256) void k_count(const int* __restrict__ receivers,
                                               int* __restrict__ deg) {
    int e = blockIdx.x * 256 + threadIdx.x;
    if (e < N_EDGES) atomicAdd(&deg[receivers[e]], 1);
}

__global__ __launch_bounds__(1024) void k_scan(const int* __restrict__ deg,
                                               int* __restrict__ offs,
                                               int* __restrict__ cursor) {
    __shared__ int sums[1024];
    const int t = threadIdx.x;
    const int CH = 10;  // 1024*10 >= 10000
    int base = t * CH;
    int local[CH];
    int s = 0;
    #pragma unroll
    for (int j = 0; j < CH; ++j) {
        int v = (base + j < N_NODES) ? deg[base + j] : 0;
        local[j] = s;
        s += v;
    }
    sums[t] = s;
    __syncthreads();
    for (int off = 1; off < 1024; off <<= 1) {
        int v = (t >= off) ? sums[t - off] : 0;
        __syncthreads();
        sums[t] += v;
        __syncthreads();
    }
    int carry = (t == 0) ? 0 : sums[t - 1];
    #pragma unroll
    for (int j = 0; j < CH; ++j) {
        int idx = base + j;
        if (idx < N_NODES) {
            int o = carry + local[j];
            offs[idx] = o;
            cursor[idx] = o;
        }
    }
    if (t == 1023) offs[N_NODES] = sums[1023];
}

__global__ __launch_bounds__(256) void k_fill(const int* __restrict__ receivers,
                                              int* __restrict__ cursor,
                                              int* __restrict__ eidx) {
    int e = blockIdx.x * 256 + threadIdx.x;
    if (e < N_EDGES) {
        int pos = atomicAdd(&cursor[receivers[e]], 1);
        eidx[pos] = e;
    }
}

// ---------------------------------------------------------------------------
// Kernel 2: radial MLP -> mix[E,4F].  256 edges/block, 512 threads,
// W4 half-tile (64KB) staged in LDS (unioned with h buffers).
// grid = (E/TE, 2): blockIdx.y selects g-half; layers 1-3 recomputed (cheap).
// ---------------------------------------------------------------------------
__device__ __forceinline__ void mlp_layer64(
    const float* __restrict__ src, float* __restrict__ dst,
    const float* __restrict__ W, const float* __restrict__ b,
    int u0, int egrp)
{
    float4 acc[8];
    float4 bb = *(const float4*)(b + u0);
    #pragma unroll
    for (int i = 0; i < 8; ++i) acc[i] = bb;
    for (int kt = 0; kt < 16; ++kt) {
        float4 w0 = *(const float4*)(W + (kt*4+0)*64 + u0);
        float4 w1 = *(const float4*)(W + (kt*4+1)*64 + u0);
        float4 w2 = *(const float4*)(W + (kt*4+2)*64 + u0);
        float4 w3 = *(const float4*)(W + (kt*4+3)*64 + u0);
        #pragma unroll
        for (int i = 0; i < 8; ++i) {
            int e = egrp + i * 32;
            float4 h = *(const float4*)(src + e * HPAD + kt * 4);
            fma4(acc[i], h.x, w0); fma4(acc[i], h.y, w1);
            fma4(acc[i], h.z, w2); fma4(acc[i], h.w, w3);
        }
    }
    #pragma unroll
    for (int i = 0; i < 8; ++i) {
        int e = egrp + i * 32;
        float4 r;
        r.x = nsilu(acc[i].x); r.y = nsilu(acc[i].y);
        r.z = nsilu(acc[i].z); r.w = nsilu(acc[i].w);
        *(float4*)(dst + e * HPAD + u0) = r;
    }
}

template <typename MT>
__global__ __launch_bounds__(512, 2) void k_mlp(
    const float* __restrict__ re,
    const float* __restrict__ W1, const float* __restrict__ b1,
    const float* __restrict__ W2, const float* __restrict__ b2,
    const float* __restrict__ W3, const float* __restrict__ b3,
    const float* __restrict__ W4, const float* __restrict__ b4,
    MT* __restrict__ mix)
{
    __shared__ float hA[TE * HPAD];      // h1 then h3
    __shared__ float hB[TE * HPAD];      // h2, then W4 half-tile (64*256 <= TE*HPAD)
    __shared__ float sre[TE * 8];

    const int t = threadIdx.x;
    const int e0 = blockIdx.x * TE;
    const int gh = blockIdx.y * 256;     // g half offset

    // stage radial embeddings (TE*8 floats = 512 float4)
    ((float4*)sre)[t] = ((const float4*)(re + (size_t)e0 * 8))[t];
    __syncthreads();

    const int uslot = t & 15;
    const int egrp  = t >> 4;            // 0..31
    const int u0 = uslot * 4;

    // ---- layer 1 (K=8): sre -> hA
    {
        float4 w[8];
        #pragma unroll
        for (int k = 0; k < 8; ++k) w[k] = *(const float4*)(W1 + k * 64 + u0);
        float4 bb = *(const float4*)(b1 + u0);
        #pragma unroll
        for (int i = 0; i < 8; ++i) {
            int e = egrp + i * 32;
            const float* rp = sre + e * 8;
            float4 a = bb;
            #pragma unroll
            for (int k = 0; k < 8; ++k) fma4(a, rp[k], w[k]);
            float4 r;
            r.x = nsilu(a.x); r.y = nsilu(a.y); r.z = nsilu(a.z); r.w = nsilu(a.w);
            *(float4*)(hA + e * HPAD + u0) = r;
        }
    }
    __syncthreads();
    mlp_layer64(hA, hB, W2, b2, u0, egrp);   // layer 2: hA -> hB
    __syncthreads();
    mlp_layer64(hB, hA, W3, b3, u0, egrp);   // layer 3: hB -> hA (= h3)
    __syncthreads();

    // ---- stage W4 half-tile [64][256] into hB
    {
        float4* dst = (float4*)hB;
        for (int idx = t; idx < 64 * 64; idx += 512) {   // 4096 float4
            int k = idx >> 6, c4 = idx & 63;
            dst[k * 64 + c4] = *(const float4*)(W4 + (size_t)k * 512 + gh + c4 * 4);
        }
    }
    __syncthreads();

    // ---- layer 4: mix = h3 @ W4h + b4, tiled 4e x 8g per thread, 4 passes
    const int eg2 = t & 15;
    const int gs  = t >> 4;              // 0..31
    float4 bb0 = *(const float4*)(b4 + gh + gs * 8);
    float4 bb1 = *(const float4*)(b4 + gh + gs * 8 + 4);
    for (int p = 0; p < 4; ++p) {
        float4 acc0[4], acc1[4];
        #pragma unroll
        for (int i = 0; i < 4; ++i) { acc0[i] = bb0; acc1[i] = bb1; }
        for (int k2 = 0; k2 < 32; ++k2) {
            const float* wp = hB + (2 * k2) * 256 + gs * 8;
            float4 w0a = *(const float4*)(wp);
            float4 w0b = *(const float4*)(wp + 4);
            float4 w1a = *(const float4*)(wp + 256);
            float4 w1b = *(const float4*)(wp + 260);
            #pragma unroll
            for (int i = 0; i < 4; ++i) {
                int e = p * 64 + eg2 + i * 16;
                float2 h = *(const float2*)(hA + e * HPAD + 2 * k2);
                fma4(acc0[i], h.x, w0a); fma4(acc0[i], h.y, w1a);
                fma4(acc1[i], h.x, w0b); fma4(acc1[i], h.y, w1b);
            }
        }
        #pragma unroll
        for (int i = 0; i < 4; ++i) {
            int e = p * 64 + eg2 + i * 16;
            size_t base = (size_t)(e0 + e) * 512 + gh + gs * 8;
            store4m(mix + base, acc0[i]);
            store4m(mix + base + 4, acc1[i]);
        }
    }
}

// ---------------------------------------------------------------------------
// Kernel 3: per-node gather over CSR edge list (no atomics).
// ---------------------------------------------------------------------------
template <typename MT>
__global__ __launch_bounds__(128) void k_gather(
    const MT* __restrict__ mix, const float* __restrict__ vectors,
    const int* __restrict__ senders,
    const float* __restrict__ s_buf, const float* __restrict__ v_buf,
    const int* __restrict__ offs, const int* __restrict__ eidx,
    float* __restrict__ agg_s, float* __restrict__ agg_v)
{
    const int n = blockIdx.x;
    const int f = threadIdx.x;
    const int beg = offs[n], end = offs[n + 1];
    const float inv_sqrt3 = 0.5773502691896258f;

    float as0 = 0, as1 = 0;
    float av00 = 0, av01 = 0, av02 = 0, av10 = 0, av11 = 0, av12 = 0;

    for (int p = beg; p < end; ++p) {
        int e = eidx[p];
        int snd = senders[e];
        float vx = vectors[e * 3 + 0], vy = vectors[e * 3 + 1], vz = vectors[e * 3 + 2];
        float rn = sqrtf(vx * vx + vy * vy + vz * vz) + 1e-12f;
        float y0 = vx / rn, y1 = vy / rn, y2 = vz / rn;

        const MT* mp = mix + (size_t)e * 512;
        float m0 = loadm(mp + f);
        float m1 = loadm(mp + 128 + f);
        float m2 = loadm(mp + 256 + f);
        float m3 = loadm(mp + 384 + f);

        float sg = s_buf[(size_t)snd * F + f];
        const float* vgp = v_buf + ((size_t)snd * F + f) * 3;
        float vg0 = vgp[0], vg1 = vgp[1], vg2 = vgp[2];

        as0 += m0 * sg;
        as1 += m3 * (vg0 * y0 + vg1 * y1 + vg2 * y2) * inv_sqrt3;
        float w1s = m1 * sg;
        av00 += w1s * y0; av01 += w1s * y1; av02 += w1s * y2;
        av10 += m2 * vg0; av11 += m2 * vg1; av12 += m2 * vg2;
    }
    agg_s[(size_t)n * 256 + f] = as0;
    agg_s[(size_t)n * 256 + 128 + f] = as1;
    float* ap = agg_v + ((size_t)n * 256 + f) * 3;
    ap[0] = av00; ap[1] = av01; ap[2] = av02;
    float* ap2 = agg_v + ((size_t)n * 256 + 128 + f) * 3;
    ap2[0] = av10; ap2[1] = av11; ap2[2] = av12;
}

// ---------------------------------------------------------------------------
// Kernel 4: linear_down + contraction + post + readout. NB nodes/block.
// ---------------------------------------------------------------------------
__global__ __launch_bounds__(128) void k_node_post(
    const float* __restrict__ agg_s, const float* __restrict__ agg_v,
    const float* __restrict__ Wds, const float* __restrict__ Wdv,
    const float* __restrict__ Wsc, const float* __restrict__ Wpost,
    const float* __restrict__ Wro1, const float* __restrict__ Wro2,
    const float* __restrict__ selfc, const int* __restrict__ counts,
    float* __restrict__ out)
{
    const int n0 = blockIdx.x * NB;
    const int g = threadIdx.x;
    __shared__ float sas[NB][256];
    __shared__ float sav0[NB][256], sav1[NB][256], sav2[NB][256];
    __shared__ float ssc[NB][F];
    __shared__ float sfeat[NB][F];
    __shared__ float shr[NB][16];

    #pragma unroll
    for (int i = 0; i < NB; ++i) {
        size_t n = n0 + i;
        sas[i][g] = agg_s[n * 256 + g];
        sas[i][128 + g] = agg_s[n * 256 + 128 + g];
        const float* ap = agg_v + n * 256 * 3;
        sav0[i][g] = ap[g * 3 + 0];
        sav1[i][g] = ap[g * 3 + 1];
        sav2[i][g] = ap[g * 3 + 2];
        sav0[i][128 + g] = ap[(128 + g) * 3 + 0];
        sav1[i][128 + g] = ap[(128 + g) * 3 + 1];
        sav2[i][128 + g] = ap[(128 + g) * 3 + 2];
    }
    __syncthreads();

    float s2[NB], v0a[NB], v1a[NB], v2a[NB];
    #pragma unroll
    for (int i = 0; i < NB; ++i) { s2[i]=0; v0a[i]=0; v1a[i]=0; v2a[i]=0; }

    for (int k4 = 0; k4 < 64; ++k4) {
        int k = k4 * 4;
        float wds0 = Wds[(k+0)*F+g], wds1 = Wds[(k+1)*F+g];
        float wds2 = Wds[(k+2)*F+g], wds3 = Wds[(k+3)*F+g];
        float wdv0 = Wdv[(k+0)*F+g], wdv1 = Wdv[(k+1)*F+g];
        float wdv2 = Wdv[(k+2)*F+g], wdv3 = Wdv[(k+3)*F+g];
        #pragma unroll
        for (int i = 0; i < NB; ++i) {
            float4 a = *(const float4*)&sas[i][k];
            float4 b0 = *(const float4*)&sav0[i][k];
            float4 b1v = *(const float4*)&sav1[i][k];
            float4 b2v = *(const float4*)&sav2[i][k];
            s2[i]  += a.x*wds0 + a.y*wds1 + a.z*wds2 + a.w*wds3;
            v0a[i] += b0.x*wdv0 + b0.y*wdv1 + b0.z*wdv2 + b0.w*wdv3;
            v1a[i] += b1v.x*wdv0 + b1v.y*wdv1 + b1v.z*wdv2 + b1v.w*wdv3;
            v2a[i] += b2v.x*wdv0 + b2v.y*wdv1 + b2v.z*wdv2 + b2v.w*wdv3;
        }
    }

    const float scale = 0.17677669529663687f * 0.0625f;   // EPS / sqrt(2F)
    #pragma unroll
    for (int i = 0; i < NB; ++i) {
        float s = s2[i] * scale;
        float w0 = v0a[i] * scale, w1 = v1a[i] * scale, w2 = v2a[i] * scale;
        float vv = w0 * w0 + w1 * w1 + w2 * w2;
        const float* wsc = Wsc + (size_t)species_of(n0 + i, counts) * 5 * F;
        float sc = wsc[0*F+g]*s + wsc[1*F+g]*(s*s) + wsc[2*F+g]*vv
                 + wsc[3*F+g]*(s*s*s) + wsc[4*F+g]*(s*vv);
        ssc[i][g] = sc;
    }
    __syncthreads();

    float accP[NB];
    #pragma unroll
    for (int i = 0; i < NB; ++i) accP[i] = 0;
    for (int f4 = 0; f4 < 32; ++f4) {
        int f = f4 * 4;
        float wp0 = Wpost[(f+0)*F+g], wp1 = Wpost[(f+1)*F+g];
        float wp2 = Wpost[(f+2)*F+g], wp3 = Wpost[(f+3)*F+g];
        #pragma unroll
        for (int i = 0; i < NB; ++i) {
            float4 x = *(const float4*)&ssc[i][f];
            accP[i] += x.x*wp0 + x.y*wp1 + x.z*wp2 + x.w*wp3;
        }
    }
    const float isf = 0.08838834764831845f;
    #pragma unroll
    for (int i = 0; i < NB; ++i) {
        size_t n = n0 + i;
        float feat = accP[i] * isf + selfc[n * F + g];
        out[N_NODES + n * F + g] = feat;
        sfeat[i][g] = feat;
    }
    __syncthreads();

    // readout: 8 nodes x 16 units
    {
        int i = g >> 4, u = g & 15;
        float a = 0;
        for (int f4 = 0; f4 < 32; ++f4) {
            int f = f4 * 4;
            float4 x = *(const float4*)&sfeat[i][f];
            a += x.x * Wro1[(f+0)*16+u] + x.y * Wro1[(f+1)*16+u]
               + x.z * Wro1[(f+2)*16+u] + x.w * Wro1[(f+3)*16+u];
        }
        shr[i][u] = nsilu(a * isf);
    }
    __syncthreads();

    if (g < NB) {
        float a = 0;
        #pragma unroll
        for (int j = 0; j < 16; ++j) a += shr[g][j] * Wro2[j];
        out[n0 + g] = a * 0.25f;   // 1/sqrt(16)
    }
}

// ---------------------------------------------------------------------------

extern "C" void kernel_launch(void* const* d_in, const int* in_sizes, int n_in,
                              void* d_out, int out_size, void* d_ws, size_t ws_size,
                              hipStream_t stream) {
    const float* vectors      = (const float*)d_in[0];
    const float* node_scalars = (const float*)d_in[1];
    const float* node_vectors = (const float*)d_in[2];
    const float* radial       = (const float*)d_in[3];
    const float* W_up_s       = (const float*)d_in[4];
    const float* W_up_v       = (const float*)d_in[5];
    const float* W1 = (const float*)d_in[6];
    const float* b1 = (const float*)d_in[7];
    const float* W2 = (const float*)d_in[8];
    const float* b2 = (const float*)d_in[9];
    const float* W3 = (const float*)d_in[10];
    const float* b3 = (const float*)d_in[11];
    const float* W4 = (const float*)d_in[12];
    const float* b4 = (const float*)d_in[13];
    const float* Wds  = (const float*)d_in[14];
    const float* Wdv  = (const float*)d_in[15];
    const float* Wz   = (const float*)d_in[16];
    const float* Wsc  = (const float*)d_in[17];
    const float* Wpost= (const float*)d_in[18];
    const float* Wro1 = (const float*)d_in[19];
    const float* Wro2 = (const float*)d_in[20];
    const int* senders   = (const int*)d_in[21];
    const int* receivers = (const int*)d_in[22];
    const int* counts    = (const int*)d_in[23];
    float* out = (float*)d_out;

    const size_t NF = (size_t)N_NODES * F;
    const size_t mix_elems = (size_t)N_EDGES * 512;
    const size_t float_elems = 13 * NF;                 // s,v,selfc,agg_s,agg_v
    const size_t int_elems = N_NODES + (N_NODES + 1) + N_NODES + N_EDGES;
    const size_t tail_bytes = float_elems * 4 + ((int_elems + 3) & ~3ull) * 4;
    const size_t need32 = mix_elems * 4 + tail_bytes;
    const bool mix32 = (ws_size >= need32);
    const size_t mix_bytes = mix32 ? mix_elems * 4 : mix_elems * 2;

    char* base = (char*)d_ws;
    float* s_buf = (float*)(base + mix_bytes);
    float* v_buf = s_buf + NF;
    float* selfc = v_buf + 3 * NF;
    float* agg_s = selfc + NF;
    float* agg_v = agg_s + 2 * NF;
    int* deg    = (int*)(agg_v + 6 * NF);
    int* offs   = deg + N_NODES;
    int* cursor = offs + N_NODES + 1;
    int* eidx   = cursor + N_NODES;

    // CSR build
    hipMemsetAsync(deg, 0, N_NODES * sizeof(int), stream);
    k_count<<<(N_EDGES + 255) / 256, 256, 0, stream>>>(receivers, deg);
    k_scan<<<1, 1024, 0, stream>>>(deg, offs, cursor);
    k_fill<<<(N_EDGES + 255) / 256, 256, 0, stream>>>(receivers, cursor, eidx);

    k_node_up<<<N_NODES / NB, 128, 0, stream>>>(
        node_scalars, node_vectors, W_up_s, W_up_v, Wz, counts,
        s_buf, v_buf, selfc);

    dim3 mg(N_EDGES / TE, 2);
    if (mix32) {
        float* mix = (float*)base;
        k_mlp<float><<<mg, 512, 0, stream>>>(radial, W1, b1, W2, b2, W3, b3, W4, b4, mix);
        k_gather<float><<<N_NODES, 128, 0, stream>>>(
            mix, vectors, senders, s_buf, v_buf, offs, eidx, agg_s, agg_v);
    } else {
        __hip_bfloat16* mix = (__hip_bfloat16*)base;
        k_mlp<__hip_bfloat16><<<mg, 512, 0, stream>>>(radial, W1, b1, W2, b2, W3, b3, W4, b4, mix);
        k_gather<__hip_bfloat16><<<N_NODES, 128, 0, stream>>>(
            mix, vectors, senders, s_buf, v_buf, offs, eidx, agg_s, agg_v);
    }

    k_node_post<<<N_NODES / NB, 128, 0, stream>>>(
        agg_s, agg_v, Wds, Wdv, Wsc, Wpost, Wro1, Wro2, selfc, counts, out);
}

// Round 3
// 463.408 us; speedup vs baseline: 3.6587x; 1.4044x over previous
//
#include <hip/hip_runtime.h>
#include <hip/hip_bf16.h>
#include <math.h>

#define N_NODES 10000
#define N_EDGES 160000
#define F 128
#define NB 8          // nodes per block in node kernels
#define TE 128        // edges per block in k_mlp
#define HS 72         // fp16 row stride for h tiles in LDS (bank-uniform)

typedef _Float16 v8h __attribute__((ext_vector_type(8)));
typedef _Float16 v4h __attribute__((ext_vector_type(4)));
typedef float    v4f __attribute__((ext_vector_type(4)));

__device__ __forceinline__ float nsilu(float x) {
    return 1.679177f * (x / (1.0f + expf(-x)));
}

__device__ __forceinline__ void fma4(float4& a, float s, const float4& b) {
    a.x = fmaf(s, b.x, a.x); a.y = fmaf(s, b.y, a.y);
    a.z = fmaf(s, b.z, a.z); a.w = fmaf(s, b.w, a.w);
}

__device__ __forceinline__ int species_of(int n, const int* __restrict__ counts) {
    int c0 = counts[0];
    int c01 = c0 + counts[1];
    int c012 = c01 + counts[2];
    return (n >= c0) + (n >= c01) + (n >= c012);
}

// ---------------------------------------------------------------------------
// Kernel 1: per-node linear_up + species skip. NB nodes per block, 128 thr.
// v_buf output is PLANAR: [n][3][F].
// ---------------------------------------------------------------------------
__global__ __launch_bounds__(128) void k_node_up(
    const float* __restrict__ ns, const float* __restrict__ nv,
    const float* __restrict__ Wup_s, const float* __restrict__ Wup_v,
    const float* __restrict__ Wz, const int* __restrict__ counts,
    float* __restrict__ s_buf, float* __restrict__ v_buf, float* __restrict__ selfc)
{
    const int n0 = blockIdx.x * NB;
    const int g = threadIdx.x;
    __shared__ float ss[NB][F];
    __shared__ float sv0[NB][F], sv1[NB][F], sv2[NB][F];

    #pragma unroll
    for (int i = 0; i < NB; ++i) {
        ss[i][g] = ns[(size_t)(n0 + i) * F + g];
        const float* vp = nv + (size_t)(n0 + i) * F * 3;
        sv0[i][g] = vp[g * 3 + 0];
        sv1[i][g] = vp[g * 3 + 1];
        sv2[i][g] = vp[g * 3 + 2];
    }
    __syncthreads();

    int spec0 = species_of(n0, counts);
    int specL = species_of(n0 + NB - 1, counts);
    bool uni = (spec0 == specL);
    const float* wzb = Wz + (size_t)spec0 * F * F;

    float accS[NB], accZ[NB], a0[NB], a1[NB], a2[NB];
    #pragma unroll
    for (int i = 0; i < NB; ++i) { accS[i]=0; accZ[i]=0; a0[i]=0; a1[i]=0; a2[i]=0; }

    for (int f4 = 0; f4 < F / 4; ++f4) {
        int f = f4 * 4;
        float ws0 = Wup_s[(f+0)*F+g], ws1 = Wup_s[(f+1)*F+g];
        float ws2 = Wup_s[(f+2)*F+g], ws3 = Wup_s[(f+3)*F+g];
        float wv0 = Wup_v[(f+0)*F+g], wv1 = Wup_v[(f+1)*F+g];
        float wv2 = Wup_v[(f+2)*F+g], wv3 = Wup_v[(f+3)*F+g];
        float wz0 = 0, wz1 = 0, wz2 = 0, wz3 = 0;
        if (uni) {
            wz0 = wzb[(f+0)*F+g]; wz1 = wzb[(f+1)*F+g];
            wz2 = wzb[(f+2)*F+g]; wz3 = wzb[(f+3)*F+g];
        }
        #pragma unroll
        for (int i = 0; i < NB; ++i) {
            float4 xs = *(const float4*)&ss[i][f];
            float4 x0 = *(const float4*)&sv0[i][f];
            float4 x1 = *(const float4*)&sv1[i][f];
            float4 x2 = *(const float4*)&sv2[i][f];
            accS[i] += xs.x*ws0 + xs.y*ws1 + xs.z*ws2 + xs.w*ws3;
            a0[i]   += x0.x*wv0 + x0.y*wv1 + x0.z*wv2 + x0.w*wv3;
            a1[i]   += x1.x*wv0 + x1.y*wv1 + x1.z*wv2 + x1.w*wv3;
            a2[i]   += x2.x*wv0 + x2.y*wv1 + x2.z*wv2 + x2.w*wv3;
            if (uni) accZ[i] += xs.x*wz0 + xs.y*wz1 + xs.z*wz2 + xs.w*wz3;
        }
    }
    if (!uni) {
        #pragma unroll
        for (int i = 0; i < NB; ++i) {
            const float* wz = Wz + (size_t)species_of(n0 + i, counts) * F * F;
            float a = 0;
            for (int f = 0; f < F; ++f) a += ss[i][f] * wz[f * F + g];
            accZ[i] = a;
        }
    }
    const float isf = 0.08838834764831845f;  // 1/sqrt(128)
    #pragma unroll
    for (int i = 0; i < NB; ++i) {
        size_t n = n0 + i;
        selfc[n * F + g] = accZ[i] * isf;
        s_buf[n * F + g] = accS[i] * isf;
        v_buf[(n * 3 + 0) * F + g] = a0[i] * isf;
        v_buf[(n * 3 + 1) * F + g] = a1[i] * isf;
        v_buf[(n * 3 + 2) * F + g] = a2[i] * isf;
    }
}

// ---------------------------------------------------------------------------
// CSR build
// ---------------------------------------------------------------------------
__global__ __launch_bounds__(256) void k_count(const int* __restrict__ receivers,
                                               int* __restrict__ deg) {
    int e = blockIdx.x * 256 + threadIdx.x;
    if (e < N_EDGES) atomicAdd(&deg[receivers[e]], 1);
}

__global__ __launch_bounds__(1024) void k_scan(const int* __restrict__ deg,
                                               int* __restrict__ offs,
                                               int* __restrict__ cursor) {
    __shared__ int sums[1024];
    const int t = threadIdx.x;
    const int CH = 10;
    int base = t * CH;
    int local[CH];
    int s = 0;
    #pragma unroll
    for (int j = 0; j < CH; ++j) {
        int v = (base + j < N_NODES) ? deg[base + j] : 0;
        local[j] = s;
        s += v;
    }
    sums[t] = s;
    __syncthreads();
    for (int off = 1; off < 1024; off <<= 1) {
        int v = (t >= off) ? sums[t - off] : 0;
        __syncthreads();
        sums[t] += v;
        __syncthreads();
    }
    int carry = (t == 0) ? 0 : sums[t - 1];
    #pragma unroll
    for (int j = 0; j < CH; ++j) {
        int idx = base + j;
        if (idx < N_NODES) {
            int o = carry + local[j];
            offs[idx] = o;
            cursor[idx] = o;
        }
    }
    if (t == 1023) offs[N_NODES] = sums[1023];
}

// k_fill also normalizes `vectors` IN PLACE (harness restores inputs before
// every launch; normalization is idempotent anyway).
__global__ __launch_bounds__(256) void k_fill(const int* __restrict__ receivers,
                                              int* __restrict__ cursor,
                                              int* __restrict__ eidx,
                                              float* __restrict__ vectors) {
    int e = blockIdx.x * 256 + threadIdx.x;
    if (e < N_EDGES) {
        int pos = atomicAdd(&cursor[receivers[e]], 1);
        eidx[pos] = e;
        float vx = vectors[e * 3 + 0];
        float vy = vectors[e * 3 + 1];
        float vz = vectors[e * 3 + 2];
        float rn = sqrtf(vx * vx + vy * vy + vz * vz) + 1e-12f;
        float inv = 1.0f / rn;
        vectors[e * 3 + 0] = vx * inv;
        vectors[e * 3 + 1] = vy * inv;
        vectors[e * 3 + 2] = vz * inv;
    }
}

// ---------------------------------------------------------------------------
// Prep: transpose weights to n-major fp16; permute W4 columns so mix layout
// becomes [e][f][4] (g_new = (g_old&127)*4 + (g_old>>7)).
// ---------------------------------------------------------------------------
__global__ __launch_bounds__(256) void k_prep(
    const float* __restrict__ W2, const float* __restrict__ W3,
    const float* __restrict__ W4, const float* __restrict__ b4,
    _Float16* __restrict__ W2t, _Float16* __restrict__ W3t,
    _Float16* __restrict__ W4t, float* __restrict__ b4p)
{
    int idx = blockIdx.x * 256 + threadIdx.x;
    if (idx < 32768) {                       // W4t[g_new][k]
        int gn = idx >> 6, k = idx & 63;
        int go = (gn & 3) * 128 + (gn >> 2);
        W4t[idx] = (_Float16)W4[k * 512 + go];
    } else if (idx < 36864) {                // W2t[u][k]
        int j = idx - 32768;
        int u = j >> 6, k = j & 63;
        W2t[j] = (_Float16)W2[k * 64 + u];
    } else if (idx < 40960) {                // W3t[u][k]
        int j = idx - 36864;
        int u = j >> 6, k = j & 63;
        W3t[j] = (_Float16)W3[k * 64 + u];
    } else if (idx < 41472) {                // b4p[g_new]
        int j = idx - 40960;
        int go = (j & 3) * 128 + (j >> 2);
        b4p[j] = b4[go];
    }
}

// ---------------------------------------------------------------------------
// Kernel 2: radial MLP via fp16 MFMA. 128 edges/block, 256 threads (4 waves).
// Layer1 (K=8) in VALU fp32 -> hA fp16; layers 2/3: MFMA with W2t/W3t B-frags
// in regs; layer4: each wave owns 128 of the 512 outputs, B-frags in regs.
// mix layout: [e][f*4 + path] fp16 (permutation folded into W4t).
// ---------------------------------------------------------------------------
__device__ __forceinline__ void mfma_layer64(
    const _Float16* src, _Float16* dst,      // LDS tiles, row stride HS
    const _Float16* __restrict__ Wt,         // [64][64] n-major fp16
    const float* __restrict__ b,             // [64] f32
    int w, int q, int c)
{
    v8h B[4][2];
    float bias[4];
    #pragma unroll
    for (int nt = 0; nt < 4; ++nt) {
        B[nt][0] = *(const v8h*)(Wt + (nt * 16 + c) * 64 + q * 8);
        B[nt][1] = *(const v8h*)(Wt + (nt * 16 + c) * 64 + 32 + q * 8);
        bias[nt] = b[nt * 16 + c];
    }
    #pragma unroll
    for (int mi = 0; mi < 2; ++mi) {
        int mt = 2 * w + mi;
        v8h a0 = *(const v8h*)(src + (mt * 16 + c) * HS + q * 8);
        v8h a1 = *(const v8h*)(src + (mt * 16 + c) * HS + 32 + q * 8);
        #pragma unroll
        for (int nt = 0; nt < 4; ++nt) {
            v4f acc = {bias[nt], bias[nt], bias[nt], bias[nt]};
            acc = __builtin_amdgcn_mfma_f32_16x16x32_f16(a0, B[nt][0], acc, 0, 0, 0);
            acc = __builtin_amdgcn_mfma_f32_16x16x32_f16(a1, B[nt][1], acc, 0, 0, 0);
            #pragma unroll
            for (int r = 0; r < 4; ++r)
                dst[(mt * 16 + q * 4 + r) * HS + nt * 16 + c] = (_Float16)nsilu(acc[r]);
        }
    }
}

__global__ __launch_bounds__(256) void k_mlp(
    const float* __restrict__ re,
    const float* __restrict__ W1, const float* __restrict__ b1,
    const _Float16* __restrict__ W2t, const float* __restrict__ b2,
    const _Float16* __restrict__ W3t, const float* __restrict__ b3,
    const _Float16* __restrict__ W4t, const float* __restrict__ b4p,
    _Float16* __restrict__ mix)
{
    __shared__ float sre[TE * 8];
    __shared__ _Float16 hA[TE * HS];
    __shared__ _Float16 hB[TE * HS];

    const int t = threadIdx.x;
    const int e0 = blockIdx.x * TE;

    ((float4*)sre)[t] = ((const float4*)(re + (size_t)e0 * 8))[t];
    __syncthreads();

    // ---- layer 1 (K=8, VALU fp32) -> hA fp16
    {
        const int uslot = t & 15;
        const int egrp = t >> 4;             // 0..15
        const int u0 = uslot * 4;
        float4 w[8];
        #pragma unroll
        for (int k = 0; k < 8; ++k) w[k] = *(const float4*)(W1 + k * 64 + u0);
        float4 bb = *(const float4*)(b1 + u0);
        #pragma unroll
        for (int i = 0; i < 8; ++i) {
            int e = egrp + i * 16;
            const float* rp = sre + e * 8;
            float4 a = bb;
            #pragma unroll
            for (int k = 0; k < 8; ++k) fma4(a, rp[k], w[k]);
            v4h r = {(_Float16)nsilu(a.x), (_Float16)nsilu(a.y),
                     (_Float16)nsilu(a.z), (_Float16)nsilu(a.w)};
            *(v4h*)(hA + e * HS + u0) = r;
        }
    }
    __syncthreads();

    const int lane = t & 63;
    const int w = t >> 6;                    // wave 0..3
    const int c = lane & 15;                 // MFMA col / m within tile
    const int q = lane >> 4;                 // quad

    // layers 2,3: each wave owns m-tiles {2w, 2w+1} end-to-end (no barrier)
    mfma_layer64(hA, hB, W2t, b2, w, q, c);
    mfma_layer64(hB, hA, W3t, b3, w, q, c);
    __syncthreads();                         // layer4 reads ALL rows of hA

    // ---- layer 4: wave w owns n-tiles [8w, 8w+8)
    v8h B4[8][2];
    float bias4[8];
    #pragma unroll
    for (int j = 0; j < 8; ++j) {
        int g = (8 * w + j) * 16 + c;
        B4[j][0] = *(const v8h*)(W4t + g * 64 + q * 8);
        B4[j][1] = *(const v8h*)(W4t + g * 64 + 32 + q * 8);
        bias4[j] = b4p[g];
    }
    for (int mt = 0; mt < 8; ++mt) {
        v8h a0 = *(const v8h*)(hA + (mt * 16 + c) * HS + q * 8);
        v8h a1 = *(const v8h*)(hA + (mt * 16 + c) * HS + 32 + q * 8);
        size_t rowbase = (size_t)(e0 + mt * 16 + q * 4) * 512;
        #pragma unroll
        for (int j = 0; j < 8; ++j) {
            v4f acc = {bias4[j], bias4[j], bias4[j], bias4[j]};
            acc = __builtin_amdgcn_mfma_f32_16x16x32_f16(a0, B4[j][0], acc, 0, 0, 0);
            acc = __builtin_amdgcn_mfma_f32_16x16x32_f16(a1, B4[j][1], acc, 0, 0, 0);
            int gcol = (8 * w + j) * 16 + c;
            #pragma unroll
            for (int r = 0; r < 4; ++r)
                mix[rowbase + (size_t)r * 512 + gcol] = (_Float16)acc[r];
        }
    }
}

// ---------------------------------------------------------------------------
// Kernel 3: per-node gather over CSR (no atomics). mix: [e][f][4] fp16.
// vectors are pre-normalized. v_buf planar [n][3][F]; agg_v planar [n][6][F].
// ---------------------------------------------------------------------------
__global__ __launch_bounds__(128) void k_gather(
    const _Float16* __restrict__ mix, const float* __restrict__ vectors,
    const int* __restrict__ senders,
    const float* __restrict__ s_buf, const float* __restrict__ v_buf,
    const int* __restrict__ offs, const int* __restrict__ eidx,
    float* __restrict__ agg_s, float* __restrict__ agg_v)
{
    const int n = blockIdx.x;
    const int f = threadIdx.x;
    const int beg = offs[n], end = offs[n + 1];
    const float inv_sqrt3 = 0.5773502691896258f;

    float as0 = 0, as1 = 0;
    float av00 = 0, av01 = 0, av02 = 0, av10 = 0, av11 = 0, av12 = 0;

    for (int p = beg; p < end; ++p) {
        int e = eidx[p];
        int snd = senders[e];
        float y0 = vectors[e * 3 + 0];
        float y1 = vectors[e * 3 + 1];
        float y2 = vectors[e * 3 + 2];

        union { uint2 u; _Float16 h[4]; } mu;
        mu.u = *(const uint2*)(mix + (size_t)e * 512 + f * 4);
        float m0 = (float)mu.h[0];
        float m1 = (float)mu.h[1];
        float m2 = (float)mu.h[2];
        float m3 = (float)mu.h[3];

        float sg = s_buf[(size_t)snd * F + f];
        const float* vb = v_buf + (size_t)snd * 3 * F;
        float vg0 = vb[0 * F + f];
        float vg1 = vb[1 * F + f];
        float vg2 = vb[2 * F + f];

        as0 += m0 * sg;
        as1 += m3 * (vg0 * y0 + vg1 * y1 + vg2 * y2) * inv_sqrt3;
        float w1s = m1 * sg;
        av00 += w1s * y0; av01 += w1s * y1; av02 += w1s * y2;
        av10 += m2 * vg0; av11 += m2 * vg1; av12 += m2 * vg2;
    }
    agg_s[(size_t)n * 256 + f] = as0;
    agg_s[(size_t)n * 256 + 128 + f] = as1;
    float* av = agg_v + (size_t)n * 768;
    av[0 * F + f] = av00; av[1 * F + f] = av01; av[2 * F + f] = av02;
    av[3 * F + f] = av10; av[4 * F + f] = av11; av[5 * F + f] = av12;
}

// ---------------------------------------------------------------------------
// Kernel 4: linear_down + contraction + post + readout. NB nodes/block.
// agg_v planar [n][6][F] (slot = half*3 + component).
// ---------------------------------------------------------------------------
__global__ __launch_bounds__(128) void k_node_post(
    const float* __restrict__ agg_s, const float* __restrict__ agg_v,
    const float* __restrict__ Wds, const float* __restrict__ Wdv,
    const float* __restrict__ Wsc, const float* __restrict__ Wpost,
    const float* __restrict__ Wro1, const float* __restrict__ Wro2,
    const float* __restrict__ selfc, const int* __restrict__ counts,
    float* __restrict__ out)
{
    const int n0 = blockIdx.x * NB;
    const int g = threadIdx.x;
    __shared__ float sas[NB][256];
    __shared__ float sav0[NB][256], sav1[NB][256], sav2[NB][256];
    __shared__ float ssc[NB][F];
    __shared__ float sfeat[NB][F];
    __shared__ float shr[NB][16];

    #pragma unroll
    for (int i = 0; i < NB; ++i) {
        size_t n = n0 + i;
        sas[i][g] = agg_s[n * 256 + g];
        sas[i][128 + g] = agg_s[n * 256 + 128 + g];
        const float* av = agg_v + n * 768;
        sav0[i][g]       = av[0 * F + g];
        sav1[i][g]       = av[1 * F + g];
        sav2[i][g]       = av[2 * F + g];
        sav0[i][128 + g] = av[3 * F + g];
        sav1[i][128 + g] = av[4 * F + g];
        sav2[i][128 + g] = av[5 * F + g];
    }
    __syncthreads();

    float s2[NB], v0a[NB], v1a[NB], v2a[NB];
    #pragma unroll
    for (int i = 0; i < NB; ++i) { s2[i]=0; v0a[i]=0; v1a[i]=0; v2a[i]=0; }

    for (int k4 = 0; k4 < 64; ++k4) {
        int k = k4 * 4;
        float wds0 = Wds[(k+0)*F+g], wds1 = Wds[(k+1)*F+g];
        float wds2 = Wds[(k+2)*F+g], wds3 = Wds[(k+3)*F+g];
        float wdv0 = Wdv[(k+0)*F+g], wdv1 = Wdv[(k+1)*F+g];
        float wdv2 = Wdv[(k+2)*F+g], wdv3 = Wdv[(k+3)*F+g];
        #pragma unroll
        for (int i = 0; i < NB; ++i) {
            float4 a = *(const float4*)&sas[i][k];
            float4 b0 = *(const float4*)&sav0[i][k];
            float4 b1v = *(const float4*)&sav1[i][k];
            float4 b2v = *(const float4*)&sav2[i][k];
            s2[i]  += a.x*wds0 + a.y*wds1 + a.z*wds2 + a.w*wds3;
            v0a[i] += b0.x*wdv0 + b0.y*wdv1 + b0.z*wdv2 + b0.w*wdv3;
            v1a[i] += b1v.x*wdv0 + b1v.y*wdv1 + b1v.z*wdv2 + b1v.w*wdv3;
            v2a[i] += b2v.x*wdv0 + b2v.y*wdv1 + b2v.z*wdv2 + b2v.w*wdv3;
        }
    }

    const float scale = 0.17677669529663687f * 0.0625f;   // EPS / sqrt(2F)
    #pragma unroll
    for (int i = 0; i < NB; ++i) {
        float s = s2[i] * scale;
        float w0 = v0a[i] * scale, w1 = v1a[i] * scale, w2 = v2a[i] * scale;
        float vv = w0 * w0 + w1 * w1 + w2 * w2;
        const float* wsc = Wsc + (size_t)species_of(n0 + i, counts) * 5 * F;
        float sc = wsc[0*F+g]*s + wsc[1*F+g]*(s*s) + wsc[2*F+g]*vv
                 + wsc[3*F+g]*(s*s*s) + wsc[4*F+g]*(s*vv);
        ssc[i][g] = sc;
    }
    __syncthreads();

    float accP[NB];
    #pragma unroll
    for (int i = 0; i < NB; ++i) accP[i] = 0;
    for (int f4 = 0; f4 < 32; ++f4) {
        int f = f4 * 4;
        float wp0 = Wpost[(f+0)*F+g], wp1 = Wpost[(f+1)*F+g];
        float wp2 = Wpost[(f+2)*F+g], wp3 = Wpost[(f+3)*F+g];
        #pragma unroll
        for (int i = 0; i < NB; ++i) {
            float4 x = *(const float4*)&ssc[i][f];
            accP[i] += x.x*wp0 + x.y*wp1 + x.z*wp2 + x.w*wp3;
        }
    }
    const float isf = 0.08838834764831845f;
    #pragma unroll
    for (int i = 0; i < NB; ++i) {
        size_t n = n0 + i;
        float feat = accP[i] * isf + selfc[n * F + g];
        out[N_NODES + n * F + g] = feat;
        sfeat[i][g] = feat;
    }
    __syncthreads();

    {
        int i = g >> 4, u = g & 15;
        float a = 0;
        for (int f4 = 0; f4 < 32; ++f4) {
            int f = f4 * 4;
            float4 x = *(const float4*)&sfeat[i][f];
            a += x.x * Wro1[(f+0)*16+u] + x.y * Wro1[(f+1)*16+u]
               + x.z * Wro1[(f+2)*16+u] + x.w * Wro1[(f+3)*16+u];
        }
        shr[i][u] = nsilu(a * isf);
    }
    __syncthreads();

    if (g < NB) {
        float a = 0;
        #pragma unroll
        for (int j = 0; j < 16; ++j) a += shr[g][j] * Wro2[j];
        out[n0 + g] = a * 0.25f;   // 1/sqrt(16)
    }
}

// ---------------------------------------------------------------------------

extern "C" void kernel_launch(void* const* d_in, const int* in_sizes, int n_in,
                              void* d_out, int out_size, void* d_ws, size_t ws_size,
                              hipStream_t stream) {
    float* vectors            = (float*)d_in[0];     // normalized in place by k_fill
    const float* node_scalars = (const float*)d_in[1];
    const float* node_vectors = (const float*)d_in[2];
    const float* radial       = (const float*)d_in[3];
    const float* W_up_s       = (const float*)d_in[4];
    const float* W_up_v       = (const float*)d_in[5];
    const float* W1 = (const float*)d_in[6];
    const float* b1 = (const float*)d_in[7];
    const float* W2 = (const float*)d_in[8];
    const float* b2 = (const float*)d_in[9];
    const float* W3 = (const float*)d_in[10];
    const float* b3 = (const float*)d_in[11];
    const float* W4 = (const float*)d_in[12];
    const float* b4 = (const float*)d_in[13];
    const float* Wds  = (const float*)d_in[14];
    const float* Wdv  = (const float*)d_in[15];
    const float* Wz   = (const float*)d_in[16];
    const float* Wsc  = (const float*)d_in[17];
    const float* Wpost= (const float*)d_in[18];
    const float* Wro1 = (const float*)d_in[19];
    const float* Wro2 = (const float*)d_in[20];
    const int* senders   = (const int*)d_in[21];
    const int* receivers = (const int*)d_in[22];
    const int* counts    = (const int*)d_in[23];
    float* out = (float*)d_out;

    const size_t NF = (size_t)N_NODES * F;

    char* base = (char*)d_ws;
    _Float16* mix = (_Float16*)base;                           // E*512 fp16
    float* s_buf = (float*)(base + (size_t)N_EDGES * 512 * 2);
    float* v_buf = s_buf + NF;          // planar [n][3][F]
    float* selfc = v_buf + 3 * NF;
    float* agg_s = selfc + NF;          // [n][2][F]
    float* agg_v = agg_s + 2 * NF;      // planar [n][6][F]
    int* deg    = (int*)(agg_v + 6 * NF);
    int* offs   = deg + N_NODES;
    int* cursor = offs + N_NODES + 1;
    int* eidx   = cursor + N_NODES;
    _Float16* W2t = (_Float16*)(eidx + N_EDGES);   // [64][64]
    _Float16* W3t = W2t + 4096;                    // [64][64]
    _Float16* W4t = W3t + 4096;                    // [512][64] permuted
    float* b4p = (float*)(W4t + 512 * 64);         // [512] permuted

    hipMemsetAsync(deg, 0, N_NODES * sizeof(int), stream);
    k_count<<<(N_EDGES + 255) / 256, 256, 0, stream>>>(receivers, deg);
    k_scan<<<1, 1024, 0, stream>>>(deg, offs, cursor);
    k_fill<<<(N_EDGES + 255) / 256, 256, 0, stream>>>(receivers, cursor, eidx, vectors);
    k_prep<<<162, 256, 0, stream>>>(W2, W3, W4, b4, W2t, W3t, W4t, b4p);

    k_node_up<<<N_NODES / NB, 128, 0, stream>>>(
        node_scalars, node_vectors, W_up_s, W_up_v, Wz, counts,
        s_buf, v_buf, selfc);

    k_mlp<<<N_EDGES / TE, 256, 0, stream>>>(
        radial, W1, b1, W2t, b2, W3t, b3, W4t, b4p, mix);

    k_gather<<<N_NODES, 128, 0, stream>>>(
        mix, vectors, senders, s_buf, v_buf, offs, eidx, agg_s, agg_v);

    k_node_post<<<N_NODES / NB, 128, 0, stream>>>(
        agg_s, agg_v, Wds, Wdv, Wsc, Wpost, Wro1, Wro2, selfc, counts, out);
}

// Round 4
// 335.250 us; speedup vs baseline: 5.0573x; 1.3823x over previous
//
#include <hip/hip_runtime.h>
#include <hip/hip_bf16.h>
#include <math.h>

#define N_NODES 10000
#define N_EDGES 160000
#define F 128
#define TE 128        // edges per block in k_mlp
#define HS 72         // fp16 row stride for h tiles in LDS (bank-uniform)

typedef _Float16 v8h __attribute__((ext_vector_type(8)));
typedef _Float16 v4h __attribute__((ext_vector_type(4)));
typedef float    v4f __attribute__((ext_vector_type(4)));

__device__ __forceinline__ float nsilu(float x) {
    return 1.679177f * (x / (1.0f + expf(-x)));
}

__device__ __forceinline__ void fma4(float4& a, float s, const float4& b) {
    a.x = fmaf(s, b.x, a.x); a.y = fmaf(s, b.y, a.y);
    a.z = fmaf(s, b.z, a.z); a.w = fmaf(s, b.w, a.w);
}

__device__ __forceinline__ int species_of(int n, const int* __restrict__ counts) {
    int c0 = counts[0];
    int c01 = c0 + counts[1];
    int c012 = c01 + counts[2];
    return (n >= c0) + (n >= c01) + (n >= c012);
}

// ---------------------------------------------------------------------------
// CSR build
// ---------------------------------------------------------------------------
__global__ __launch_bounds__(256) void k_count(const int* __restrict__ receivers,
                                               int* __restrict__ deg) {
    int e = blockIdx.x * 256 + threadIdx.x;
    if (e < N_EDGES) atomicAdd(&deg[receivers[e]], 1);
}

__global__ __launch_bounds__(1024) void k_scan(const int* __restrict__ deg,
                                               int* __restrict__ offs,
                                               int* __restrict__ cursor) {
    __shared__ int sums[1024];
    const int t = threadIdx.x;
    const int CH = 10;
    int base = t * CH;
    int local[CH];
    int s = 0;
    #pragma unroll
    for (int j = 0; j < CH; ++j) {
        int v = (base + j < N_NODES) ? deg[base + j] : 0;
        local[j] = s;
        s += v;
    }
    sums[t] = s;
    __syncthreads();
    for (int off = 1; off < 1024; off <<= 1) {
        int v = (t >= off) ? sums[t - off] : 0;
        __syncthreads();
        sums[t] += v;
        __syncthreads();
    }
    int carry = (t == 0) ? 0 : sums[t - 1];
    #pragma unroll
    for (int j = 0; j < CH; ++j) {
        int idx = base + j;
        if (idx < N_NODES) {
            int o = carry + local[j];
            offs[idx] = o;
            cursor[idx] = o;
        }
    }
    if (t == 1023) offs[N_NODES] = sums[1023];
}

// k_fill also normalizes `vectors` IN PLACE (idempotent; harness restores
// inputs before every launch).
__global__ __launch_bounds__(256) void k_fill(const int* __restrict__ receivers,
                                              int* __restrict__ cursor,
                                              int* __restrict__ eidx,
                                              float* __restrict__ vectors) {
    int e = blockIdx.x * 256 + threadIdx.x;
    if (e < N_EDGES) {
        int pos = atomicAdd(&cursor[receivers[e]], 1);
        eidx[pos] = e;
        float vx = vectors[e * 3 + 0];
        float vy = vectors[e * 3 + 1];
        float vz = vectors[e * 3 + 2];
        float rn = sqrtf(vx * vx + vy * vy + vz * vz) + 1e-12f;
        float inv = 1.0f / rn;
        vectors[e * 3 + 0] = vx * inv;
        vectors[e * 3 + 1] = vy * inv;
        vectors[e * 3 + 2] = vz * inv;
    }
}

// ---------------------------------------------------------------------------
// Weight prep: everything to fp16 n-major ([out_col][k]).
// W4t permuted so mix layout = [e][f][4].
// ---------------------------------------------------------------------------
__global__ __launch_bounds__(256) void k_prep_w(
    const float* __restrict__ W2, const float* __restrict__ W3,
    const float* __restrict__ W4, const float* __restrict__ b4,
    const float* __restrict__ Wup_s, const float* __restrict__ Wup_v,
    const float* __restrict__ Wz, const float* __restrict__ Wds,
    const float* __restrict__ Wdv, const float* __restrict__ Wpost,
    _Float16* __restrict__ W2t, _Float16* __restrict__ W3t,
    _Float16* __restrict__ W4t, float* __restrict__ b4p,
    _Float16* __restrict__ Wup_s_t, _Float16* __restrict__ Wup_v_t,
    _Float16* __restrict__ Wz_t, _Float16* __restrict__ Wds_t,
    _Float16* __restrict__ Wdv_t, _Float16* __restrict__ Wpost_t)
{
    int idx = blockIdx.x * 256 + threadIdx.x;
    if (idx < 4096) {                            // W2t[u][k]
        int u = idx >> 6, k = idx & 63;
        W2t[idx] = (_Float16)W2[k * 64 + u];
    } else if (idx < 8192) {                     // W3t
        int j = idx - 4096;
        int u = j >> 6, k = j & 63;
        W3t[j] = (_Float16)W3[k * 64 + u];
    } else if (idx < 40960) {                    // W4t[g_new][k], permuted
        int j = idx - 8192;
        int gn = j >> 6, k = j & 63;
        int go = (gn & 3) * 128 + (gn >> 2);
        W4t[j] = (_Float16)W4[k * 512 + go];
    } else if (idx < 41472) {                    // b4p
        int j = idx - 40960;
        int go = (j & 3) * 128 + (j >> 2);
        b4p[j] = b4[go];
    } else if (idx < 57856) {                    // Wup_s_t[g][f]
        int j = idx - 41472;
        int g = j >> 7, f = j & 127;
        Wup_s_t[j] = (_Float16)Wup_s[f * 128 + g];
    } else if (idx < 74240) {                    // Wup_v_t
        int j = idx - 57856;
        int g = j >> 7, f = j & 127;
        Wup_v_t[j] = (_Float16)Wup_v[f * 128 + g];
    } else if (idx < 139776) {                   // Wz_t[s][g][f]
        int j = idx - 74240;
        int s = j >> 14, r = j & 16383;
        int g = r >> 7, f = r & 127;
        Wz_t[j] = (_Float16)Wz[s * 16384 + f * 128 + g];
    } else if (idx < 172544) {                   // Wds_t[g][k], K=256
        int j = idx - 139776;
        int g = j >> 8, k = j & 255;
        Wds_t[j] = (_Float16)Wds[k * 128 + g];
    } else if (idx < 205312) {                   // Wdv_t
        int j = idx - 172544;
        int g = j >> 8, k = j & 255;
        Wdv_t[j] = (_Float16)Wdv[k * 128 + g];
    } else if (idx < 221696) {                   // Wpost_t
        int j = idx - 205312;
        int g = j >> 7, f = j & 127;
        Wpost_t[j] = (_Float16)Wpost[f * 128 + g];
    }
}

// node inputs -> fp16.  nv16 rows = (n*3+c), cols f.
__global__ __launch_bounds__(256) void k_prep_a(
    const float* __restrict__ ns, const float* __restrict__ nv,
    _Float16* __restrict__ ns16, _Float16* __restrict__ nv16)
{
    int idx = blockIdx.x * 256 + threadIdx.x;
    if (idx < N_NODES * F) {
        ns16[idx] = (_Float16)ns[idx];
    } else {
        int j = idx - N_NODES * F;               // < 3N*F
        int row = j >> 7, f = j & 127;
        int n = row / 3, c = row - n * 3;
        nv16[j] = (_Float16)nv[((size_t)n * F + f) * 3 + c];
    }
}

// ---------------------------------------------------------------------------
// Generic 128-row x 128-col fp16 MFMA GEMM tile. B staged in LDS (n-major),
// A streamed from global (fp16, lda=K). out fp32 [M][128], scaled.
// sp >= 0: store only rows whose species == sp.
// ---------------------------------------------------------------------------
template <int K>
__device__ __forceinline__ void gemm_tile(
    const _Float16* __restrict__ A, const _Float16* __restrict__ Bg,
    float* __restrict__ out, int M, int row0, float scale,
    _Float16* Bl, const int* __restrict__ counts, int sp)
{
    const int t = threadIdx.x;
    constexpr int KP = K + 8;                    // padded LDS row stride
    __syncthreads();                             // safe for B restage
    for (int idx = t; idx < 128 * (K / 8); idx += 256) {
        int g = idx / (K / 8), kk = (idx % (K / 8)) * 8;
        *(v8h*)(Bl + g * KP + kk) = *(const v8h*)(Bg + g * K + kk);
    }
    __syncthreads();

    const int lane = t & 63;
    const int w = t >> 6;
    const int c = lane & 15;
    const int q = lane >> 4;

    v4f acc[2][8];
    #pragma unroll
    for (int mi = 0; mi < 2; ++mi)
        #pragma unroll
        for (int nt = 0; nt < 8; ++nt)
            acc[mi][nt] = (v4f){0.f, 0.f, 0.f, 0.f};

    for (int ch = 0; ch < K / 32; ++ch) {
        v8h a[2];
        #pragma unroll
        for (int mi = 0; mi < 2; ++mi) {
            int r = row0 + (2 * w + mi) * 16 + c;
            r = min(r, M - 1);                   // clamp; garbage rows not stored
            a[mi] = *(const v8h*)(A + (size_t)r * K + ch * 32 + q * 8);
        }
        #pragma unroll
        for (int nt = 0; nt < 8; ++nt) {
            v8h b = *(const v8h*)(Bl + (nt * 16 + c) * KP + ch * 32 + q * 8);
            acc[0][nt] = __builtin_amdgcn_mfma_f32_16x16x32_f16(a[0], b, acc[0][nt], 0, 0, 0);
            acc[1][nt] = __builtin_amdgcn_mfma_f32_16x16x32_f16(a[1], b, acc[1][nt], 0, 0, 0);
        }
    }
    #pragma unroll
    for (int mi = 0; mi < 2; ++mi) {
        #pragma unroll
        for (int r = 0; r < 4; ++r) {
            int row = row0 + (2 * w + mi) * 16 + q * 4 + r;
            bool ok = row < M;
            if (ok && sp >= 0) ok = (species_of(row, counts) == sp);
            if (ok) {
                float* op = out + (size_t)row * 128;
                #pragma unroll
                for (int nt = 0; nt < 8; ++nt)
                    op[nt * 16 + c] = acc[mi][nt][r] * scale;
            }
        }
    }
}

// grid (235, 3): y=0 s_buf, y=1 v_buf (M=3N), y=2 selfc (species B)
__global__ __launch_bounds__(256) void k_gemm_up(
    const _Float16* __restrict__ ns16, const _Float16* __restrict__ nv16,
    const _Float16* __restrict__ Wup_s_t, const _Float16* __restrict__ Wup_v_t,
    const _Float16* __restrict__ Wz_t, const int* __restrict__ counts,
    float* __restrict__ s_buf, float* __restrict__ v_buf, float* __restrict__ selfc)
{
    __shared__ _Float16 Bl[128 * 136];
    const int row0 = blockIdx.x * 128;
    const float isf = 0.08838834764831845f;      // 1/sqrt(128)
    if (blockIdx.y == 0) {
        if (row0 >= N_NODES) return;
        gemm_tile<128>(ns16, Wup_s_t, s_buf, N_NODES, row0, isf, Bl, counts, -1);
    } else if (blockIdx.y == 1) {
        gemm_tile<128>(nv16, Wup_v_t, v_buf, 3 * N_NODES, row0, isf, Bl, counts, -1);
    } else {
        if (row0 >= N_NODES) return;
        int sp0 = species_of(row0, counts);
        int sp1 = species_of(min(row0 + 127, N_NODES - 1), counts);
        for (int sp = sp0; sp <= sp1; ++sp)
            gemm_tile<128>(ns16, Wz_t + (size_t)sp * 16384, selfc,
                           N_NODES, row0, isf, Bl, counts, sp);
    }
}

// grid (235, 2): y=0 s2 = agg_s16 @ Wds_t, y=1 v2 = agg_v16 @ Wdv_t (M=3N)
__global__ __launch_bounds__(256) void k_gemm_down(
    const _Float16* __restrict__ agg_s16, const _Float16* __restrict__ agg_v16,
    const _Float16* __restrict__ Wds_t, const _Float16* __restrict__ Wdv_t,
    const int* __restrict__ counts,
    float* __restrict__ s2, float* __restrict__ v2)
{
    __shared__ _Float16 Bl[128 * 264];
    const int row0 = blockIdx.x * 128;
    if (blockIdx.y == 0) {
        if (row0 >= N_NODES) return;
        gemm_tile<256>(agg_s16, Wds_t, s2, N_NODES, row0, 1.0f, Bl, counts, -1);
    } else {
        gemm_tile<256>(agg_v16, Wdv_t, v2, 3 * N_NODES, row0, 1.0f, Bl, counts, -1);
    }
}

// ---------------------------------------------------------------------------
// Radial MLP via fp16 MFMA (unchanged from round 3; mix = [e][f][4] fp16).
// ---------------------------------------------------------------------------
__device__ __forceinline__ void mfma_layer64(
    const _Float16* src, _Float16* dst,
    const _Float16* __restrict__ Wt, const float* __restrict__ b,
    int w, int q, int c)
{
    v8h B[4][2];
    float bias[4];
    #pragma unroll
    for (int nt = 0; nt < 4; ++nt) {
        B[nt][0] = *(const v8h*)(Wt + (nt * 16 + c) * 64 + q * 8);
        B[nt][1] = *(const v8h*)(Wt + (nt * 16 + c) * 64 + 32 + q * 8);
        bias[nt] = b[nt * 16 + c];
    }
    #pragma unroll
    for (int mi = 0; mi < 2; ++mi) {
        int mt = 2 * w + mi;
        v8h a0 = *(const v8h*)(src + (mt * 16 + c) * HS + q * 8);
        v8h a1 = *(const v8h*)(src + (mt * 16 + c) * HS + 32 + q * 8);
        #pragma unroll
        for (int nt = 0; nt < 4; ++nt) {
            v4f acc = {bias[nt], bias[nt], bias[nt], bias[nt]};
            acc = __builtin_amdgcn_mfma_f32_16x16x32_f16(a0, B[nt][0], acc, 0, 0, 0);
            acc = __builtin_amdgcn_mfma_f32_16x16x32_f16(a1, B[nt][1], acc, 0, 0, 0);
            #pragma unroll
            for (int r = 0; r < 4; ++r)
                dst[(mt * 16 + q * 4 + r) * HS + nt * 16 + c] = (_Float16)nsilu(acc[r]);
        }
    }
}

__global__ __launch_bounds__(256) void k_mlp(
    const float* __restrict__ re,
    const float* __restrict__ W1, const float* __restrict__ b1,
    const _Float16* __restrict__ W2t, const float* __restrict__ b2,
    const _Float16* __restrict__ W3t, const float* __restrict__ b3,
    const _Float16* __restrict__ W4t, const float* __restrict__ b4p,
    _Float16* __restrict__ mix)
{
    __shared__ float sre[TE * 8];
    __shared__ _Float16 hA[TE * HS];
    __shared__ _Float16 hB[TE * HS];

    const int t = threadIdx.x;
    const int e0 = blockIdx.x * TE;

    ((float4*)sre)[t] = ((const float4*)(re + (size_t)e0 * 8))[t];
    __syncthreads();

    {
        const int uslot = t & 15;
        const int egrp = t >> 4;
        const int u0 = uslot * 4;
        float4 w[8];
        #pragma unroll
        for (int k = 0; k < 8; ++k) w[k] = *(const float4*)(W1 + k * 64 + u0);
        float4 bb = *(const float4*)(b1 + u0);
        #pragma unroll
        for (int i = 0; i < 8; ++i) {
            int e = egrp + i * 16;
            const float* rp = sre + e * 8;
            float4 a = bb;
            #pragma unroll
            for (int k = 0; k < 8; ++k) fma4(a, rp[k], w[k]);
            v4h r = {(_Float16)nsilu(a.x), (_Float16)nsilu(a.y),
                     (_Float16)nsilu(a.z), (_Float16)nsilu(a.w)};
            *(v4h*)(hA + e * HS + u0) = r;
        }
    }
    __syncthreads();

    const int lane = t & 63;
    const int w = t >> 6;
    const int c = lane & 15;
    const int q = lane >> 4;

    mfma_layer64(hA, hB, W2t, b2, w, q, c);
    mfma_layer64(hB, hA, W3t, b3, w, q, c);
    __syncthreads();

    v8h B4[8][2];
    float bias4[8];
    #pragma unroll
    for (int j = 0; j < 8; ++j) {
        int g = (8 * w + j) * 16 + c;
        B4[j][0] = *(const v8h*)(W4t + g * 64 + q * 8);
        B4[j][1] = *(const v8h*)(W4t + g * 64 + 32 + q * 8);
        bias4[j] = b4p[g];
    }
    for (int mt = 0; mt < 8; ++mt) {
        v8h a0 = *(const v8h*)(hA + (mt * 16 + c) * HS + q * 8);
        v8h a1 = *(const v8h*)(hA + (mt * 16 + c) * HS + 32 + q * 8);
        size_t rowbase = (size_t)(e0 + mt * 16 + q * 4) * 512;
        #pragma unroll
        for (int j = 0; j < 8; ++j) {
            v4f acc = {bias4[j], bias4[j], bias4[j], bias4[j]};
            acc = __builtin_amdgcn_mfma_f32_16x16x32_f16(a0, B4[j][0], acc, 0, 0, 0);
            acc = __builtin_amdgcn_mfma_f32_16x16x32_f16(a1, B4[j][1], acc, 0, 0, 0);
            int gcol = (8 * w + j) * 16 + c;
            #pragma unroll
            for (int r = 0; r < 4; ++r)
                mix[rowbase + (size_t)r * 512 + gcol] = (_Float16)acc[r];
        }
    }
}

// ---------------------------------------------------------------------------
// Gather over CSR. Writes fp16 agg (EPS/sqrt(2F) folded in):
//   agg_s16 [n][256]; agg_v16 rows (n*3+c), cols half*128+f.
// ---------------------------------------------------------------------------
__global__ __launch_bounds__(128) void k_gather(
    const _Float16* __restrict__ mix, const float* __restrict__ vectors,
    const int* __restrict__ senders,
    const float* __restrict__ s_buf, const float* __restrict__ v_buf,
    const int* __restrict__ offs, const int* __restrict__ eidx,
    _Float16* __restrict__ agg_s16, _Float16* __restrict__ agg_v16)
{
    const int n = blockIdx.x;
    const int f = threadIdx.x;
    const int beg = offs[n], end = offs[n + 1];
    const float inv_sqrt3 = 0.5773502691896258f;

    float as0 = 0, as1 = 0;
    float av00 = 0, av01 = 0, av02 = 0, av10 = 0, av11 = 0, av12 = 0;

    for (int p = beg; p < end; ++p) {
        int e = eidx[p];
        int snd = senders[e];
        float y0 = vectors[e * 3 + 0];
        float y1 = vectors[e * 3 + 1];
        float y2 = vectors[e * 3 + 2];

        union { uint2 u; _Float16 h[4]; } mu;
        mu.u = *(const uint2*)(mix + (size_t)e * 512 + f * 4);
        float m0 = (float)mu.h[0];
        float m1 = (float)mu.h[1];
        float m2 = (float)mu.h[2];
        float m3 = (float)mu.h[3];

        float sg = s_buf[(size_t)snd * F + f];
        const float* vb = v_buf + (size_t)snd * 384;
        float vg0 = vb[f];
        float vg1 = vb[128 + f];
        float vg2 = vb[256 + f];

        as0 += m0 * sg;
        as1 += m3 * (vg0 * y0 + vg1 * y1 + vg2 * y2) * inv_sqrt3;
        float w1s = m1 * sg;
        av00 += w1s * y0; av01 += w1s * y1; av02 += w1s * y2;
        av10 += m2 * vg0; av11 += m2 * vg1; av12 += m2 * vg2;
    }
    const float SC = 0.011048543456039804f;      // EPS / sqrt(256)
    agg_s16[(size_t)n * 256 + f]       = (_Float16)(as0 * SC);
    agg_s16[(size_t)n * 256 + 128 + f] = (_Float16)(as1 * SC);
    _Float16* av = agg_v16 + (size_t)n * 768;
    av[0 * 256 + f]       = (_Float16)(av00 * SC);
    av[0 * 256 + 128 + f] = (_Float16)(av10 * SC);
    av[1 * 256 + f]       = (_Float16)(av01 * SC);
    av[1 * 256 + 128 + f] = (_Float16)(av11 * SC);
    av[2 * 256 + f]       = (_Float16)(av02 * SC);
    av[2 * 256 + 128 + f] = (_Float16)(av12 * SC);
}

// ---------------------------------------------------------------------------
// Elementwise symmetric contraction: (s2, v2) -> sc16.
// ---------------------------------------------------------------------------
__global__ __launch_bounds__(256) void k_contract(
    const float* __restrict__ s2, const float* __restrict__ v2,
    const float* __restrict__ Wsc, const int* __restrict__ counts,
    _Float16* __restrict__ sc16)
{
    int idx = blockIdx.x * 256 + threadIdx.x;    // n*128+g
    int n = idx >> 7, g = idx & 127;
    float s = s2[idx];
    const float* vp = v2 + (size_t)n * 384;
    float a0 = vp[g], a1 = vp[128 + g], a2 = vp[256 + g];
    float vv = a0 * a0 + a1 * a1 + a2 * a2;
    const float* w = Wsc + (size_t)species_of(n, counts) * 640;
    float sc = w[g] * s + w[128 + g] * (s * s) + w[256 + g] * vv
             + w[384 + g] * (s * s * s) + w[512 + g] * (s * vv);
    sc16[idx] = (_Float16)sc;
}

// ---------------------------------------------------------------------------
// Post GEMM (sc16 @ Wpost_t * isf + selfc) with fused readout.
// ---------------------------------------------------------------------------
__global__ __launch_bounds__(256) void k_post(
    const _Float16* __restrict__ sc16, const _Float16* __restrict__ Wpost_t,
    const float* __restrict__ selfc,
    const float* __restrict__ Wro1, const float* __restrict__ Wro2,
    float* __restrict__ out)
{
    __shared__ _Float16 Bl[128 * 136];
    __shared__ float sfeat[128][132];
    __shared__ float shr[128][16];
    const int t = threadIdx.x;
    const int row0 = blockIdx.x * 128;
    const float isf = 0.08838834764831845f;

    for (int idx = t; idx < 128 * 16; idx += 256) {
        int g = idx >> 4, kk = (idx & 15) * 8;
        *(v8h*)(Bl + g * 136 + kk) = *(const v8h*)(Wpost_t + g * 128 + kk);
    }
    __syncthreads();

    const int lane = t & 63;
    const int w = t >> 6;
    const int c = lane & 15;
    const int q = lane >> 4;

    v4f acc[2][8];
    #pragma unroll
    for (int mi = 0; mi < 2; ++mi)
        #pragma unroll
        for (int nt = 0; nt < 8; ++nt)
            acc[mi][nt] = (v4f){0.f, 0.f, 0.f, 0.f};

    for (int ch = 0; ch < 4; ++ch) {
        v8h a[2];
        #pragma unroll
        for (int mi = 0; mi < 2; ++mi) {
            int r = row0 + (2 * w + mi) * 16 + c;
            r = min(r, N_NODES - 1);
            a[mi] = *(const v8h*)(sc16 + (size_t)r * 128 + ch * 32 + q * 8);
        }
        #pragma unroll
        for (int nt = 0; nt < 8; ++nt) {
            v8h b = *(const v8h*)(Bl + (nt * 16 + c) * 136 + ch * 32 + q * 8);
            acc[0][nt] = __builtin_amdgcn_mfma_f32_16x16x32_f16(a[0], b, acc[0][nt], 0, 0, 0);
            acc[1][nt] = __builtin_amdgcn_mfma_f32_16x16x32_f16(a[1], b, acc[1][nt], 0, 0, 0);
        }
    }
    #pragma unroll
    for (int mi = 0; mi < 2; ++mi) {
        #pragma unroll
        for (int r = 0; r < 4; ++r) {
            int row = row0 + (2 * w + mi) * 16 + q * 4 + r;
            int rl = (2 * w + mi) * 16 + q * 4 + r;
            if (row < N_NODES) {
                #pragma unroll
                for (int nt = 0; nt < 8; ++nt) {
                    int col = nt * 16 + c;
                    float feat = acc[mi][nt][r] * isf + selfc[(size_t)row * 128 + col];
                    out[N_NODES + (size_t)row * 128 + col] = feat;
                    sfeat[rl][col] = feat;
                }
            } else {
                #pragma unroll
                for (int nt = 0; nt < 8; ++nt) sfeat[rl][nt * 16 + c] = 0.f;
            }
        }
    }
    __syncthreads();

    for (int idx = t; idx < 2048; idx += 256) {
        int nd = idx >> 4, u = idx & 15;
        float a = 0;
        for (int f = 0; f < 128; f += 4) {
            float4 x = *(const float4*)&sfeat[nd][f];
            a += x.x * Wro1[(f + 0) * 16 + u] + x.y * Wro1[(f + 1) * 16 + u]
               + x.z * Wro1[(f + 2) * 16 + u] + x.w * Wro1[(f + 3) * 16 + u];
        }
        shr[nd][u] = nsilu(a * isf);
    }
    __syncthreads();

    if (t < 128 && row0 + t < N_NODES) {
        float a = 0;
        #pragma unroll
        for (int j = 0; j < 16; ++j) a += shr[t][j] * Wro2[j];
        out[row0 + t] = a * 0.25f;               // 1/sqrt(16)
    }
}

// ---------------------------------------------------------------------------

extern "C" void kernel_launch(void* const* d_in, const int* in_sizes, int n_in,
                              void* d_out, int out_size, void* d_ws, size_t ws_size,
                              hipStream_t stream) {
    float* vectors            = (float*)d_in[0];
    const float* node_scalars = (const float*)d_in[1];
    const float* node_vectors = (const float*)d_in[2];
    const float* radial       = (const float*)d_in[3];
    const float* W_up_s       = (const float*)d_in[4];
    const float* W_up_v       = (const float*)d_in[5];
    const float* W1 = (const float*)d_in[6];
    const float* b1 = (const float*)d_in[7];
    const float* W2 = (const float*)d_in[8];
    const float* b2 = (const float*)d_in[9];
    const float* W3 = (const float*)d_in[10];
    const float* b3 = (const float*)d_in[11];
    const float* W4 = (const float*)d_in[12];
    const float* b4 = (const float*)d_in[13];
    const float* Wds  = (const float*)d_in[14];
    const float* Wdv  = (const float*)d_in[15];
    const float* Wz   = (const float*)d_in[16];
    const float* Wsc  = (const float*)d_in[17];
    const float* Wpost= (const float*)d_in[18];
    const float* Wro1 = (const float*)d_in[19];
    const float* Wro2 = (const float*)d_in[20];
    const int* senders   = (const int*)d_in[21];
    const int* receivers = (const int*)d_in[22];
    const int* counts    = (const int*)d_in[23];
    float* out = (float*)d_out;

    const size_t NF = (size_t)N_NODES * F;

    char* base = (char*)d_ws;
    // mix region (dead after k_gather) is reused for s2/v2/sc16.
    _Float16* mix = (_Float16*)base;                     // E*512 fp16 = 163.84 MB
    float* s2   = (float*)base;                          // N*128 fp32 (after gather)
    float* v2   = s2 + NF;                               // 3N*128 fp32
    _Float16* sc16 = (_Float16*)(v2 + 3 * NF);           // N*128 fp16

    char* p = base + (size_t)N_EDGES * 512 * 2;
    _Float16* ns16 = (_Float16*)p;        p += NF * 2;
    _Float16* nv16 = (_Float16*)p;        p += 3 * NF * 2;
    float* s_buf   = (float*)p;           p += NF * 4;
    float* v_buf   = (float*)p;           p += 3 * NF * 4;   // rows (n*3+c)
    float* selfc   = (float*)p;           p += NF * 4;
    _Float16* agg_s16 = (_Float16*)p;     p += 2 * NF * 2;   // [n][256]
    _Float16* agg_v16 = (_Float16*)p;     p += 6 * NF * 2;   // rows (n*3+c) x 256
    int* deg    = (int*)p;                p += N_NODES * 4;
    int* offs   = (int*)p;                p += (N_NODES + 1) * 4;
    int* cursor = (int*)p;                p += N_NODES * 4;
    int* eidx   = (int*)p;                p += N_EDGES * 4;
    _Float16* W2t = (_Float16*)p;         p += 4096 * 2;
    _Float16* W3t = (_Float16*)p;         p += 4096 * 2;
    _Float16* W4t = (_Float16*)p;         p += 32768 * 2;
    float* b4p    = (float*)p;            p += 512 * 4;
    _Float16* Wup_s_t = (_Float16*)p;     p += 16384 * 2;
    _Float16* Wup_v_t = (_Float16*)p;     p += 16384 * 2;
    _Float16* Wz_t    = (_Float16*)p;     p += 65536 * 2;
    _Float16* Wds_t   = (_Float16*)p;     p += 32768 * 2;
    _Float16* Wdv_t   = (_Float16*)p;     p += 32768 * 2;
    _Float16* Wpost_t = (_Float16*)p;     p += 16384 * 2;

    hipMemsetAsync(deg, 0, N_NODES * sizeof(int), stream);
    k_count<<<(N_EDGES + 255) / 256, 256, 0, stream>>>(receivers, deg);
    k_scan<<<1, 1024, 0, stream>>>(deg, offs, cursor);
    k_fill<<<(N_EDGES + 255) / 256, 256, 0, stream>>>(receivers, cursor, eidx, vectors);

    k_prep_w<<<866, 256, 0, stream>>>(W2, W3, W4, b4, W_up_s, W_up_v, Wz, Wds, Wdv, Wpost,
                                      W2t, W3t, W4t, b4p, Wup_s_t, Wup_v_t, Wz_t,
                                      Wds_t, Wdv_t, Wpost_t);
    k_prep_a<<<20000, 256, 0, stream>>>(node_scalars, node_vectors, ns16, nv16);

    k_gemm_up<<<dim3(235, 3), 256, 0, stream>>>(
        ns16, nv16, Wup_s_t, Wup_v_t, Wz_t, counts, s_buf, v_buf, selfc);

    k_mlp<<<N_EDGES / TE, 256, 0, stream>>>(
        radial, W1, b1, W2t, b2, W3t, b3, W4t, b4p, mix);

    k_gather<<<N_NODES, 128, 0, stream>>>(
        mix, vectors, senders, s_buf, v_buf, offs, eidx, agg_s16, agg_v16);

    k_gemm_down<<<dim3(235, 2), 256, 0, stream>>>(
        agg_s16, agg_v16, Wds_t, Wdv_t, counts, s2, v2);

    k_contract<<<(N_NODES * F) / 256, 256, 0, stream>>>(s2, v2, Wsc, counts, sc16);

    k_post<<<(N_NODES + 127) / 128, 256, 0, stream>>>(
        sc16, Wpost_t, selfc, Wro1, Wro2, out);
}